// Round 10
// baseline (250.980 us; speedup 1.0000x reference)
//
#include <hip/hip_runtime.h>
#include <hip/hip_bf16.h>
#include <math.h>

#define NH   4
#define DH   16
#define CH   64
#define KNN  10
#define KS   4
#define NV   4096
#define NB   4
#define MHID 256
#define BN   (NB * NV)

// canonical param-buffer offsets (f32 elements)
#define P_LN1G  0
#define P_LN1B  64
#define P_LN2G  128
#define P_LN2B  192
#define P_WQKV  256
#define P_BQKV  12544
#define P_WPROJ 12736
#define P_BPROJ 16832
#define P_W1    16896
#define P_B1    33280
#define P_W2    33536
#define P_B2    49920
#define P_TOT   49984

typedef __hip_bfloat16 bf16;

__device__ __forceinline__ float b2f(bf16 x) { return __bfloat162float(x); }

__device__ __forceinline__ float cvt(const void* p, int i, int isbf) {
  return isbf ? b2f(((const bf16*)p)[i]) : ((const float*)p)[i];
}

__device__ __forceinline__ float wave_sum_f32(float v) {
#pragma unroll
  for (int m = 32; m >= 1; m >>= 1) v += __shfl_xor(v, m, 64);
  return v;
}

// lexicographic wave-min over (hi, lo) pairs (knn fallback path only)
__device__ __forceinline__ void wave_min_kv(unsigned& hi, unsigned& lo) {
#pragma unroll
  for (int m = 32; m >= 1; m >>= 1) {
    unsigned ohi = __shfl_xor(hi, m, 64);
    unsigned olo = __shfl_xor(lo, m, 64);
    if (ohi < hi || (ohi == hi && olo < lo)) { hi = ohi; lo = olo; }
  }
}

__device__ __forceinline__ float rdlane(float v, int src) {
  return __uint_as_float(__builtin_amdgcn_readlane(__float_as_uint(v), src));
}

__device__ __forceinline__ float tanh_fast(float u) {
  float e = __expf(2.0f * u);
  return 1.0f - 2.0f / (e + 1.0f);
}

// identical d2 expression everywhere (exactness anchor)
__device__ __forceinline__ float d2f(float x, float y, float z,
                                     float qx, float qy, float qz) {
  float dx = x - qx, dy = y - qy, dz = z - qz;
  return dx * dx + dy * dy + dz * dz;
}

__device__ __forceinline__ int cell_of(float x, float y, float z) {
  int cx = min(7, max(0, (int)floorf(x * 0.5f)));
  int cy = min(7, max(0, (int)floorf(y * 0.5f)));
  int cz = min(7, max(0, (int)floorf(z * 0.5f)));
  return (cz * 8 + cy) * 8 + cx;
}

// ---------------- K0: storage-dtype detection ----------------
__global__ __launch_bounds__(64) void k_detect(
    const unsigned short* __restrict__ x_u16,
    const unsigned* __restrict__ m_u32, int* __restrict__ flags)
{
  const int lane = threadIdx.x;
  int cnt = 0;
#pragma unroll
  for (int k = 0; k < 4; ++k) {
    unsigned short w = x_u16[lane * 4 + k];
    int e = (w >> 7) & 0xFF;
    cnt += (e >= 100 && e <= 140);
  }
#pragma unroll
  for (int m = 32; m >= 1; m >>= 1) cnt += __shfl_xor(cnt, m, 64);
  unsigned big = (m_u32[lane] > 1u) ? 1u : 0u;
#pragma unroll
  for (int m = 32; m >= 1; m >>= 1) big |= __shfl_xor(big, m, 64);
  if (lane == 0) { flags[0] = (cnt >= 205) ? 1 : 0; flags[1] = big ? 1 : 0; }
}

// ---------------- K0b: canonicalize inputs ----------------
__global__ __launch_bounds__(256) void k_ingest(
    const void* xin, const void* coords, const void* maskr,
    const void* ln1g, const void* ln1b, const void* ln2g, const void* ln2b,
    const void* wqkv, const void* bqkv, const void* wproj, const void* bproj,
    const void* w1, const void* b1, const void* w2, const void* b2,
    const int* __restrict__ flags,
    float* __restrict__ xcan, float* __restrict__ ccan,
    float* __restrict__ pcan, int* __restrict__ mcan)
{
  const int isbf = flags[0];
  const int m8 = flags[1];
  int id = blockIdx.x * 256 + threadIdx.x;
  const int n0 = BN * CH, n1 = NB * NV * 3, n2 = P_TOT, n3 = BN;
  if (id < n0) { xcan[id] = cvt(xin, id, isbf); return; }
  id -= n0;
  if (id < n1) { ccan[id] = cvt(coords, id, isbf); return; }
  id -= n1;
  if (id < n2) {
    const void* src; int off;
    if      (id < P_LN1B)  { src = ln1g;  off = id - P_LN1G; }
    else if (id < P_LN2G)  { src = ln1b;  off = id - P_LN1B; }
    else if (id < P_LN2B)  { src = ln2g;  off = id - P_LN2G; }
    else if (id < P_WQKV)  { src = ln2b;  off = id - P_LN2B; }
    else if (id < P_BQKV)  { src = wqkv;  off = id - P_WQKV; }
    else if (id < P_WPROJ) { src = bqkv;  off = id - P_BQKV; }
    else if (id < P_BPROJ) { src = wproj; off = id - P_WPROJ; }
    else if (id < P_W1)    { src = bproj; off = id - P_BPROJ; }
    else if (id < P_B1)    { src = w1;    off = id - P_W1; }
    else if (id < P_W2)    { src = b1;    off = id - P_B1; }
    else if (id < P_B2)    { src = w2;    off = id - P_W2; }
    else                   { src = b2;    off = id - P_B2; }
    pcan[id] = cvt(src, off, isbf);
    return;
  }
  id -= n2;
  if (id < n3) {
    mcan[id] = m8 ? (int)(((const unsigned char*)maskr)[id] != 0)
                  : (int)(((const int*)maskr)[id] != 0);
  }
}

// ---------------- K0c: per-batch uniform-grid CSR build ----------------
__global__ __launch_bounds__(256) void k_grid(
    const float* __restrict__ ccan, const int* __restrict__ mcan,
    float* __restrict__ csrX, float* __restrict__ csrY,
    float* __restrict__ csrZ, int* __restrict__ csrI,
    int* __restrict__ cellStart)
{
  __shared__ int hist[512];
  __shared__ int base_[512];
  const int b = blockIdx.x;
  const int tid = threadIdx.x;
  const float* cb = ccan + (size_t)b * NV * 3;
  const int* mb = mcan + b * NV;
  for (int i = tid; i < 512; i += 256) hist[i] = 0;
  __syncthreads();
  for (int j = tid; j < NV; j += 256) {
    if (mb[j]) {
      int c = cell_of(cb[j * 3], cb[j * 3 + 1], cb[j * 3 + 2]);
      atomicAdd(&hist[c], 1);
    }
  }
  __syncthreads();
  if (tid < 64) {
    int loc[8]; int sum = 0;
#pragma unroll
    for (int k = 0; k < 8; ++k) { loc[k] = sum; sum += hist[tid * 8 + k]; }
    int incl = sum;
#pragma unroll
    for (int off = 1; off < 64; off <<= 1) {
      int o = __shfl_up(incl, off);
      if (tid >= off) incl += o;
    }
    int excl = incl - sum;
#pragma unroll
    for (int k = 0; k < 8; ++k) base_[tid * 8 + k] = excl + loc[k];
    if (tid == 63) cellStart[b * 513 + 512] = incl;   // total valid V
  }
  __syncthreads();
  for (int i = tid; i < 512; i += 256) cellStart[b * 513 + i] = base_[i];
  for (int i = tid; i < 512; i += 256) hist[i] = 0;   // reuse as cursors
  __syncthreads();
  for (int j = tid; j < NV; j += 256) {
    if (mb[j]) {
      float x = cb[j * 3], y = cb[j * 3 + 1], z = cb[j * 3 + 2];
      int c = cell_of(x, y, z);
      int slot = base_[c] + atomicAdd(&hist[c], 1);
      size_t o = (size_t)b * NV + slot;
      csrX[o] = x; csrY[o] = y; csrZ[o] = z; csrI[o] = j;
    }
  }
}

// ---------------- K1: LN1 + QKV (wave-per-4-rows, LDS weights) ----------------
__global__ __launch_bounds__(256) void k_ln_qkv(
    const float* __restrict__ x, const float* __restrict__ pcan,
    float* __restrict__ qkv)
{
  __shared__ float wl[CH * 192];
  __shared__ float bq[192];
  const int tid = threadIdx.x;
  for (int i = tid; i < CH * 192; i += 256) wl[i] = pcan[P_WQKV + i];
  if (tid < 192) bq[tid] = pcan[P_BQKV + tid];
  __syncthreads();
  const int wave = tid >> 6, lane = tid & 63;
  const int row0 = blockIdx.x * 16 + wave * 4;
  const float gg = pcan[P_LN1G + lane], bb = pcan[P_LN1B + lane];

  float xn[4];
#pragma unroll
  for (int r = 0; r < 4; ++r) {
    float v = x[(size_t)(row0 + r) * CH + lane];
    float m = wave_sum_f32(v) * (1.0f / 64.0f);
    float d = v - m;
    float var = wave_sum_f32(d * d) * (1.0f / 64.0f);
    float rs = 1.0f / sqrtf(var + 1e-5f);
    xn[r] = d * rs * gg + bb;
  }

  const int n0 = 3 * lane;
  float a[4][3];
#pragma unroll
  for (int r = 0; r < 4; ++r) {
    a[r][0] = bq[n0]; a[r][1] = bq[n0 + 1]; a[r][2] = bq[n0 + 2];
  }
  for (int c = 0; c < CH; ++c) {
    float w0 = wl[c * 192 + n0];
    float w1 = wl[c * 192 + n0 + 1];
    float w2 = wl[c * 192 + n0 + 2];
#pragma unroll
    for (int r = 0; r < 4; ++r) {
      float s = rdlane(xn[r], c);
      a[r][0] = fmaf(s, w0, a[r][0]);
      a[r][1] = fmaf(s, w1, a[r][1]);
      a[r][2] = fmaf(s, w2, a[r][2]);
    }
  }
#pragma unroll
  for (int r = 0; r < 4; ++r) {
    size_t o = (size_t)(row0 + r) * 192 + n0;
    qkv[o] = a[r][0]; qkv[o + 1] = a[r][1]; qkv[o + 2] = a[r][2];
  }
}

// ---------------- K2: KNN via uniform grid (exact) ----------------
// Per wave (1 query): (1) shell-count to pick cube with >=10 pts; (2) T =
// exact 10th-smallest d2 of cube subset (upper bound on true 10th, ballot
// binary search); (3) visit every cell with box-min-d2 <= T+margin, append
// every point with d2 <= T (same d2f bits); (4) exact rank-by-count on
// (d2bits,j) keys = jax tie-break. Degenerate/overflow -> exact brute force.
#define KQB 4
__global__ __launch_bounds__(256) void k_knn(
    const float* __restrict__ ccan, const int* __restrict__ mcan,
    const float* __restrict__ csrX, const float* __restrict__ csrY,
    const float* __restrict__ csrZ, const int* __restrict__ csrI,
    const int* __restrict__ cellStart, int* __restrict__ nbr)
{
  __shared__ int cs[513];
  __shared__ unsigned long long sbuf[KQB][64];
  __shared__ int scnt[KQB];
  const int tid = threadIdx.x;
  const int row0 = blockIdx.x * KQB;
  const int b = row0 >> 12;
  for (int i = tid; i < 513; i += 256) cs[i] = cellStart[b * 513 + i];
  if (tid < KQB) scnt[tid] = 0;
  __syncthreads();
  const int wave = tid >> 6, lane = tid & 63;
  const int qi = (row0 & (NV - 1)) + wave;
  const float* cb = ccan + (size_t)b * NV * 3;
  const size_t gb = (size_t)b * NV;
  const float qx = cb[qi * 3], qy = cb[qi * 3 + 1], qz = cb[qi * 3 + 2];
  const int qcx = min(7, max(0, (int)floorf(qx * 0.5f)));
  const int qcy = min(7, max(0, (int)floorf(qy * 0.5f)));
  const int qcz = min(7, max(0, (int)floorf(qz * 0.5f)));
  const int V = cs[512];
  const unsigned SENT = 0x7fffffffu;

  bool fail = (V < KNN);
  float T = 1e30f;
  if (!fail) {
    // shell expansion (count only, wave-uniform)
    int s, cnt = 0;
    int x0 = 0, x1 = 7, y0 = 0, y1 = 7, z0 = 0, z1 = 7;
    for (s = 1; s <= 7; ++s) {
      z0 = max(0, qcz - s); z1 = min(7, qcz + s);
      y0 = max(0, qcy - s); y1 = min(7, qcy + s);
      x0 = max(0, qcx - s); x1 = min(7, qcx + s);
      cnt = 0;
      for (int zz = z0; zz <= z1; ++zz)
        for (int yy = y0; yy <= y1; ++yy) {
          int cbase = (zz * 8 + yy) * 8;
          cnt += cs[cbase + x1 + 1] - cs[cbase + x0];
        }
      if (cnt >= KNN) break;
    }
    if (cnt < KNN) fail = true;
    else {
      // bound pass: up to 4 subset d2 per lane
      unsigned v0 = SENT, v1 = SENT, v2 = SENT, v3 = SENT;
      int ns = 0;
      for (int zz = z0; zz <= z1; ++zz)
        for (int yy = y0; yy <= y1; ++yy) {
          int cbase = (zz * 8 + yy) * 8;
          int p0 = cs[cbase + x0], p1 = cs[cbase + x1 + 1];
          for (int p = p0 + lane; p < p1; p += 64) {
            float d2 = d2f(csrX[gb + p], csrY[gb + p], csrZ[gb + p], qx, qy, qz);
            unsigned ub = __float_as_uint(d2);
            if (ns == 0) v0 = ub; else if (ns == 1) v1 = ub;
            else if (ns == 2) v2 = ub; else if (ns == 3) v3 = ub;
            if (ns < 4) ++ns;
          }
        }
      int kept = __popcll(__ballot(v0 != SENT)) + __popcll(__ballot(v1 != SENT))
               + __popcll(__ballot(v2 != SENT)) + __popcll(__ballot(v3 != SENT));
      if (kept < KNN) fail = true;   // pathological slot overflow
      else {
        unsigned acc = 0;
#pragma unroll 1
        for (int bit = 31; bit >= 0; --bit) {
          unsigned tr = acc | (1u << bit);
          int c4 = __popcll(__ballot(v0 < tr)) + __popcll(__ballot(v1 < tr))
                 + __popcll(__ballot(v2 < tr)) + __popcll(__ballot(v3 < tr));
          if (c4 <= KNN - 1) acc = tr;
        }
        T = __uint_as_float(acc);   // exact subset 10th-smallest
      }
    }
  }

  if (!fail) {
    const float Tm = T + 1e-3f;    // cell-test margin >> box f32 rounding
    for (int cc = lane; cc < 512; cc += 64) {
      int p0 = cs[cc], p1 = cs[cc + 1];
      if (p0 == p1) continue;
      float lox = 2.f * (cc & 7), loy = 2.f * ((cc >> 3) & 7), loz = 2.f * (cc >> 6);
      float dxm = fmaxf(fmaxf(lox - qx, qx - (lox + 2.f)), 0.f);
      float dym = fmaxf(fmaxf(loy - qy, qy - (loy + 2.f)), 0.f);
      float dzm = fmaxf(fmaxf(loz - qz, qz - (loz + 2.f)), 0.f);
      if (dxm * dxm + dym * dym + dzm * dzm > Tm) continue;
      for (int p = p0; p < p1; ++p) {
        float d2 = d2f(csrX[gb + p], csrY[gb + p], csrZ[gb + p], qx, qy, qz);
        if (d2 <= T) {
          int sp = atomicAdd(&scnt[wave], 1);
          if (sp < 64)
            sbuf[wave][sp] =
                ((unsigned long long)__float_as_uint(d2) << 32) | (unsigned)csrI[gb + p];
        }
      }
    }
    int c = scnt[wave];
    if (c < KNN || c > 64) fail = true;
    else if (lane < c) {
      unsigned long long mykey = sbuf[wave][lane];
      int rank = 0;
      for (int i = 0; i < c; ++i) rank += (sbuf[wave][i] < mykey);
      if (rank < KNN)
        nbr[(size_t)(row0 + wave) * KNN + rank] = (int)(mykey & (NV - 1));
    }
  }

  if (fail) {
    // exact brute force over all NV (jax semantics: invalid -> d2=1e9)
    const int* mb = mcan + b * NV;
    unsigned long long arr[KNN];
#pragma unroll
    for (int t = 0; t < KNN; ++t) arr[t] = ~0ull;
    for (int j = lane; j < NV; j += 64) {
      float d2 = d2f(cb[j * 3], cb[j * 3 + 1], cb[j * 3 + 2], qx, qy, qz);
      if (!mb[j]) d2 = 1e9f;
      unsigned long long key =
          ((unsigned long long)__float_as_uint(d2) << 32) | (unsigned)j;
      if (key < arr[KNN - 1]) {
        arr[KNN - 1] = key;
#pragma unroll
        for (int t2 = KNN - 1; t2 > 0; --t2) {
          unsigned long long a = arr[t2 - 1], cc2 = arr[t2];
          if (cc2 < a) { arr[t2 - 1] = cc2; arr[t2] = a; }
        }
      }
    }
    unsigned myj = 0;
#pragma unroll 1
    for (int r = 0; r < KNN; ++r) {
      unsigned hi = (unsigned)(arr[0] >> 32);
      unsigned lo = (unsigned)(arr[0] & 0xffffffffu);
      wave_min_kv(hi, lo);
      if (lane == (int)(lo & 63u)) {   // owner lane of j is j&63 (stride 64)
#pragma unroll
        for (int t = 0; t < KNN - 1; ++t) arr[t] = arr[t + 1];
        arr[KNN - 1] = ~0ull;
      }
      if (lane == r) myj = lo;
    }
    if (lane < KNN)
      nbr[(size_t)(row0 + wave) * KNN + lane] = (int)(myj & (NV - 1));
  }
}

// ---------------- K3: attention + proj + residual (R9 version) ----------------
#define AROWS 4
__global__ __launch_bounds__(256) void k_attn(
    const float* __restrict__ qkv, const int* __restrict__ nbr,
    const int* __restrict__ mcan, const float* __restrict__ xcan,
    const float* __restrict__ pcan, float* __restrict__ xres)
{
  __shared__ float wp[CH * CH];   // 16 KB wproj [c][n]
  __shared__ float bp[CH];
  __shared__ float sc[AROWS][NH][KNN];
  __shared__ float wsel[AROWS][NH][KS];
  __shared__ int   isel[AROWS][NH][KS];
  __shared__ float obuf[AROWS][CH];
  __shared__ int   nb[AROWS][KNN];
  __shared__ float npen[AROWS][KNN];
  const int tid = threadIdx.x;
  {
    const float4* src = (const float4*)(pcan + P_WPROJ);
    float4* dst = (float4*)wp;
    for (int i = tid; i < CH * CH / 4; i += 256) dst[i] = src[i];
    if (tid < CH) bp[tid] = pcan[P_BPROJ + tid];
  }
  const int wave = tid >> 6, lane = tid & 63;
  const int row = blockIdx.x * AROWS + wave;
  const int b = row / NV;

  if (lane < KNN) {
    int j = nbr[(size_t)row * KNN + lane] & (NV - 1);
    nb[wave][lane] = j;
    npen[wave][lane] = mcan[b * NV + j] ? 0.0f : -1e9f;
  }
  __syncthreads();

  if (lane < NH * KNN) {
    int h = lane / KNN, kk = lane % KNN;
    int j = nb[wave][kk];
    const float* qp = qkv + (size_t)row * 192 + h * DH;
    const float* kp = qkv + ((size_t)(b * NV + j)) * 192 + 64 + h * DH;
    float acc = 0.f;
#pragma unroll
    for (int d = 0; d < DH; ++d) acc += qp[d] * kp[d];
    sc[wave][h][kk] = acc * 0.25f + npen[wave][kk];
  }
  __syncthreads();

  if (lane < NH) {
    int h = lane;
    float sv[KS]; int sj[KS];
    unsigned used = 0;
#pragma unroll
    for (int r = 0; r < KS; ++r) {
      float best = -INFINITY; int bi = 0;
#pragma unroll
      for (int kk = 0; kk < KNN; ++kk) {
        float s = sc[wave][h][kk];
        if (!(used & (1u << kk)) && s > best) { best = s; bi = kk; }
      }
      used |= 1u << bi; sv[r] = best; sj[r] = bi;
    }
    float mx = sv[0];
    float e[KS], sum = 0.f;
#pragma unroll
    for (int r = 0; r < KS; ++r) { e[r] = expf(sv[r] - mx); sum += e[r]; }
    float inv = 1.0f / sum;
#pragma unroll
    for (int r = 0; r < KS; ++r) {
      wsel[wave][h][r] = e[r] * inv;
      isel[wave][h][r] = nb[wave][sj[r]];
    }
  }
  __syncthreads();

  {
    int h = lane >> 4, d = lane & 15;
    float o = 0.f;
#pragma unroll
    for (int r = 0; r < KS; ++r) {
      int j = isel[wave][h][r];
      o += wsel[wave][h][r] * qkv[((size_t)(b * NV + j)) * 192 + 128 + h * DH + d];
    }
    obuf[wave][lane] = o;
  }
  __syncthreads();

  {
    float acc = bp[lane];
#pragma unroll 4
    for (int cc = 0; cc < CH; ++cc)
      acc = fmaf(obuf[wave][cc], wp[cc * CH + lane], acc);
    float a = mcan[row] ? acc : 0.0f;
    xres[(size_t)row * CH + lane] = 0.5f * a + xcan[(size_t)row * CH + lane];
  }
}

// ---------------- K4: LN2 + MLP + residual (R9 version) ----------------
__global__ __launch_bounds__(256) void k_mlp(
    const float* __restrict__ xres, const float* __restrict__ pcan,
    const int* __restrict__ flags, void* __restrict__ out)
{
  __shared__ unsigned short w1b[CH * MHID];   // [c][n] 32 KB bf16
  const int tid = threadIdx.x;
  for (int i = tid; i < CH * MHID; i += 256)
    w1b[i] = __bfloat16_as_ushort(__float2bfloat16(pcan[P_W1 + i]));
  __syncthreads();
  const int wave = tid >> 6, lane = tid & 63;
  const int row0 = blockIdx.x * 16 + wave * 4;
  const float gg = pcan[P_LN2G + lane], bb = pcan[P_LN2B + lane];

  float xn[4], xv[4];
#pragma unroll
  for (int r = 0; r < 4; ++r) {
    float v = xres[(size_t)(row0 + r) * CH + lane];
    xv[r] = v;
    float m = wave_sum_f32(v) * (1.0f / 64.0f);
    float d = v - m;
    float var = wave_sum_f32(d * d) * (1.0f / 64.0f);
    float rs = 1.0f / sqrtf(var + 1e-5f);
    xn[r] = d * rs * gg + bb;
  }

  const int n0 = 4 * lane;
  float g[4][4];
  {
    float4 bi = *(const float4*)(pcan + P_B1 + n0);
#pragma unroll
    for (int r = 0; r < 4; ++r) {
      g[r][0] = bi.x; g[r][1] = bi.y; g[r][2] = bi.z; g[r][3] = bi.w;
    }
  }
  for (int c = 0; c < CH; ++c) {
    ushort4 w4 = *(const ushort4*)&w1b[c * MHID + n0];
    float w0 = b2f(__ushort_as_bfloat16(w4.x));
    float w1 = b2f(__ushort_as_bfloat16(w4.y));
    float w2 = b2f(__ushort_as_bfloat16(w4.z));
    float w3 = b2f(__ushort_as_bfloat16(w4.w));
#pragma unroll
    for (int r = 0; r < 4; ++r) {
      float s = rdlane(xn[r], c);
      g[r][0] = fmaf(s, w0, g[r][0]);
      g[r][1] = fmaf(s, w1, g[r][1]);
      g[r][2] = fmaf(s, w2, g[r][2]);
      g[r][3] = fmaf(s, w3, g[r][3]);
    }
  }
#pragma unroll
  for (int r = 0; r < 4; ++r)
#pragma unroll
    for (int i = 0; i < 4; ++i) {
      float t = g[r][i];
      float u = 0.7978845608028654f * (t + 0.044715f * t * t * t);
      g[r][i] = 0.5f * t * (1.0f + tanh_fast(u));
    }

  float acc2[4];
  {
    float bo = pcan[P_B2 + lane];
#pragma unroll
    for (int r = 0; r < 4; ++r) acc2[r] = bo;
  }
  const float* w2p = pcan + P_W2 + lane;
#pragma unroll 2
  for (int hb = 0; hb < MHID / 4; ++hb) {
#pragma unroll
    for (int i = 0; i < 4; ++i) {
      float wv = w2p[(hb * 4 + i) * CH];
#pragma unroll
      for (int r = 0; r < 4; ++r)
        acc2[r] = fmaf(rdlane(g[r][i], hb), wv, acc2[r]);
    }
  }
#pragma unroll
  for (int r = 0; r < 4; ++r) {
    float o = 0.5f * acc2[r] + xv[r];
    size_t idx = (size_t)(row0 + r) * CH + lane;
    if (flags[0]) ((bf16*)out)[idx] = __float2bfloat16(o);
    else          ((float*)out)[idx] = o;
  }
}

extern "C" void kernel_launch(void* const* d_in, const int* in_sizes, int n_in,
                              void* d_out, int out_size, void* d_ws, size_t ws_size,
                              hipStream_t stream)
{
  char* ws = (char*)d_ws;
  float* qkv   = (float*)(ws);
  float* xres  = (float*)(ws + 12582912);
  float* xcan  = (float*)(ws + 16777216);
  float* ccan  = (float*)(ws + 20971520);
  float* pcan  = (float*)(ws + 21168128);
  int*   mcan  = (int*)  (ws + 21368064);
  int*   nbr   = (int*)  (ws + 21433600);
  int*   flags = (int*)  (ws + 22088960);
  float* csrX  = (float*)(ws + 22089728);
  float* csrY  = (float*)(ws + 22155264);
  float* csrZ  = (float*)(ws + 22220800);
  int*   csrI  = (int*)  (ws + 22286336);
  int*   cellS = (int*)  (ws + 22351872);

  k_detect<<<1, 64, 0, stream>>>((const unsigned short*)d_in[0],
                                 (const unsigned*)d_in[2], flags);
  const int total = BN * CH + NB * NV * 3 + P_TOT + BN;
  k_ingest<<<(total + 255) / 256, 256, 0, stream>>>(
      d_in[0], d_in[1], d_in[2], d_in[3], d_in[4], d_in[5], d_in[6],
      d_in[7], d_in[8], d_in[9], d_in[10], d_in[11], d_in[12], d_in[13], d_in[14],
      flags, xcan, ccan, pcan, mcan);
  k_grid<<<NB, 256, 0, stream>>>(ccan, mcan, csrX, csrY, csrZ, csrI, cellS);
  k_ln_qkv<<<BN / 16, 256, 0, stream>>>(xcan, pcan, qkv);
  k_knn<<<BN / KQB, 256, 0, stream>>>(ccan, mcan, csrX, csrY, csrZ, csrI,
                                      cellS, nbr);
  k_attn<<<BN / AROWS, 256, 0, stream>>>(qkv, nbr, mcan, xcan, pcan, xres);
  k_mlp<<<BN / 16, 256, 0, stream>>>(xres, pcan, flags, d_out);
}

// Round 11
// 239.415 us; speedup vs baseline: 1.0483x; 1.0483x over previous
//
#include <hip/hip_runtime.h>
#include <hip/hip_bf16.h>
#include <math.h>

#define NH   4
#define DH   16
#define CH   64
#define KNN  10
#define KS   4
#define NV   4096
#define NB   4
#define MHID 256
#define BN   (NB * NV)

// canonical param-buffer offsets (f32 elements)
#define P_LN1G  0
#define P_LN1B  64
#define P_LN2G  128
#define P_LN2B  192
#define P_WQKV  256
#define P_BQKV  12544
#define P_WPROJ 12736
#define P_BPROJ 16832
#define P_W1    16896
#define P_B1    33280
#define P_W2    33536
#define P_B2    49920
#define P_TOT   49984

typedef __hip_bfloat16 bf16;

__device__ __forceinline__ float b2f(bf16 x) { return __bfloat162float(x); }

__device__ __forceinline__ float cvt(const void* p, int i, int isbf) {
  return isbf ? b2f(((const bf16*)p)[i]) : ((const float*)p)[i];
}

__device__ __forceinline__ float wave_sum_f32(float v) {
#pragma unroll
  for (int m = 32; m >= 1; m >>= 1) v += __shfl_xor(v, m, 64);
  return v;
}

// lexicographic wave-min over (hi, lo) pairs (knn fallback path only)
__device__ __forceinline__ void wave_min_kv(unsigned& hi, unsigned& lo) {
#pragma unroll
  for (int m = 32; m >= 1; m >>= 1) {
    unsigned ohi = __shfl_xor(hi, m, 64);
    unsigned olo = __shfl_xor(lo, m, 64);
    if (ohi < hi || (ohi == hi && olo < lo)) { hi = ohi; lo = olo; }
  }
}

__device__ __forceinline__ float rdlane(float v, int src) {
  return __uint_as_float(__builtin_amdgcn_readlane(__float_as_uint(v), src));
}

__device__ __forceinline__ float tanh_fast(float u) {
  float e = __expf(2.0f * u);
  return 1.0f - 2.0f / (e + 1.0f);
}

// identical d2 expression everywhere (exactness anchor)
__device__ __forceinline__ float d2f(float x, float y, float z,
                                     float qx, float qy, float qz) {
  float dx = x - qx, dy = y - qy, dz = z - qz;
  return dx * dx + dy * dy + dz * dz;
}

__device__ __forceinline__ int cell_of(float x, float y, float z) {
  int cx = min(7, max(0, (int)floorf(x * 0.5f)));
  int cy = min(7, max(0, (int)floorf(y * 0.5f)));
  int cz = min(7, max(0, (int)floorf(z * 0.5f)));
  return (cz * 8 + cy) * 8 + cx;
}

// ---------------- K0: storage-dtype detection ----------------
__global__ __launch_bounds__(64) void k_detect(
    const unsigned short* __restrict__ x_u16,
    const unsigned* __restrict__ m_u32, int* __restrict__ flags)
{
  const int lane = threadIdx.x;
  int cnt = 0;
#pragma unroll
  for (int k = 0; k < 4; ++k) {
    unsigned short w = x_u16[lane * 4 + k];
    int e = (w >> 7) & 0xFF;
    cnt += (e >= 100 && e <= 140);
  }
#pragma unroll
  for (int m = 32; m >= 1; m >>= 1) cnt += __shfl_xor(cnt, m, 64);
  unsigned big = (m_u32[lane] > 1u) ? 1u : 0u;
#pragma unroll
  for (int m = 32; m >= 1; m >>= 1) big |= __shfl_xor(big, m, 64);
  if (lane == 0) { flags[0] = (cnt >= 205) ? 1 : 0; flags[1] = big ? 1 : 0; }
}

// ---------------- K0b: canonicalize inputs ----------------
__global__ __launch_bounds__(256) void k_ingest(
    const void* xin, const void* coords, const void* maskr,
    const void* ln1g, const void* ln1b, const void* ln2g, const void* ln2b,
    const void* wqkv, const void* bqkv, const void* wproj, const void* bproj,
    const void* w1, const void* b1, const void* w2, const void* b2,
    const int* __restrict__ flags,
    float* __restrict__ xcan, float* __restrict__ ccan,
    float* __restrict__ pcan, int* __restrict__ mcan)
{
  const int isbf = flags[0];
  const int m8 = flags[1];
  int id = blockIdx.x * 256 + threadIdx.x;
  const int n0 = BN * CH, n1 = NB * NV * 3, n2 = P_TOT, n3 = BN;
  if (id < n0) { xcan[id] = cvt(xin, id, isbf); return; }
  id -= n0;
  if (id < n1) { ccan[id] = cvt(coords, id, isbf); return; }
  id -= n1;
  if (id < n2) {
    const void* src; int off;
    if      (id < P_LN1B)  { src = ln1g;  off = id - P_LN1G; }
    else if (id < P_LN2G)  { src = ln1b;  off = id - P_LN1B; }
    else if (id < P_LN2B)  { src = ln2g;  off = id - P_LN2G; }
    else if (id < P_WQKV)  { src = ln2b;  off = id - P_LN2B; }
    else if (id < P_BQKV)  { src = wqkv;  off = id - P_WQKV; }
    else if (id < P_WPROJ) { src = bqkv;  off = id - P_BQKV; }
    else if (id < P_BPROJ) { src = wproj; off = id - P_WPROJ; }
    else if (id < P_W1)    { src = bproj; off = id - P_BPROJ; }
    else if (id < P_B1)    { src = w1;    off = id - P_W1; }
    else if (id < P_W2)    { src = b1;    off = id - P_B1; }
    else if (id < P_B2)    { src = w2;    off = id - P_W2; }
    else                   { src = b2;    off = id - P_B2; }
    pcan[id] = cvt(src, off, isbf);
    return;
  }
  id -= n2;
  if (id < n3) {
    mcan[id] = m8 ? (int)(((const unsigned char*)maskr)[id] != 0)
                  : (int)(((const int*)maskr)[id] != 0);
  }
}

// ---------------- K0c: per-batch uniform-grid CSR build ----------------
__global__ __launch_bounds__(256) void k_grid(
    const float* __restrict__ ccan, const int* __restrict__ mcan,
    float* __restrict__ csrX, float* __restrict__ csrY,
    float* __restrict__ csrZ, int* __restrict__ csrI,
    int* __restrict__ cellStart)
{
  __shared__ int hist[512];
  __shared__ int base_[512];
  const int b = blockIdx.x;
  const int tid = threadIdx.x;
  const float* cb = ccan + (size_t)b * NV * 3;
  const int* mb = mcan + b * NV;
  for (int i = tid; i < 512; i += 256) hist[i] = 0;
  __syncthreads();
  for (int j = tid; j < NV; j += 256) {
    if (mb[j]) {
      int c = cell_of(cb[j * 3], cb[j * 3 + 1], cb[j * 3 + 2]);
      atomicAdd(&hist[c], 1);
    }
  }
  __syncthreads();
  if (tid < 64) {
    int loc[8]; int sum = 0;
#pragma unroll
    for (int k = 0; k < 8; ++k) { loc[k] = sum; sum += hist[tid * 8 + k]; }
    int incl = sum;
#pragma unroll
    for (int off = 1; off < 64; off <<= 1) {
      int o = __shfl_up(incl, off);
      if (tid >= off) incl += o;
    }
    int excl = incl - sum;
#pragma unroll
    for (int k = 0; k < 8; ++k) base_[tid * 8 + k] = excl + loc[k];
    if (tid == 63) cellStart[b * 513 + 512] = incl;   // total valid V
  }
  __syncthreads();
  for (int i = tid; i < 512; i += 256) cellStart[b * 513 + i] = base_[i];
  for (int i = tid; i < 512; i += 256) hist[i] = 0;   // reuse as cursors
  __syncthreads();
  for (int j = tid; j < NV; j += 256) {
    if (mb[j]) {
      float x = cb[j * 3], y = cb[j * 3 + 1], z = cb[j * 3 + 2];
      int c = cell_of(x, y, z);
      int slot = base_[c] + atomicAdd(&hist[c], 1);
      size_t o = (size_t)b * NV + slot;
      csrX[o] = x; csrY[o] = y; csrZ[o] = z; csrI[o] = j;
    }
  }
}

// ---------------- K1: LN1 + QKV (wave-per-4-rows, LDS weights) ----------------
__global__ __launch_bounds__(256) void k_ln_qkv(
    const float* __restrict__ x, const float* __restrict__ pcan,
    float* __restrict__ qkv)
{
  __shared__ float wl[CH * 192];
  __shared__ float bq[192];
  const int tid = threadIdx.x;
  for (int i = tid; i < CH * 192; i += 256) wl[i] = pcan[P_WQKV + i];
  if (tid < 192) bq[tid] = pcan[P_BQKV + tid];
  __syncthreads();
  const int wave = tid >> 6, lane = tid & 63;
  const int row0 = blockIdx.x * 16 + wave * 4;
  const float gg = pcan[P_LN1G + lane], bb = pcan[P_LN1B + lane];

  float xn[4];
#pragma unroll
  for (int r = 0; r < 4; ++r) {
    float v = x[(size_t)(row0 + r) * CH + lane];
    float m = wave_sum_f32(v) * (1.0f / 64.0f);
    float d = v - m;
    float var = wave_sum_f32(d * d) * (1.0f / 64.0f);
    float rs = 1.0f / sqrtf(var + 1e-5f);
    xn[r] = d * rs * gg + bb;
  }

  const int n0 = 3 * lane;
  float a[4][3];
#pragma unroll
  for (int r = 0; r < 4; ++r) {
    a[r][0] = bq[n0]; a[r][1] = bq[n0 + 1]; a[r][2] = bq[n0 + 2];
  }
  for (int c = 0; c < CH; ++c) {
    float w0 = wl[c * 192 + n0];
    float w1 = wl[c * 192 + n0 + 1];
    float w2 = wl[c * 192 + n0 + 2];
#pragma unroll
    for (int r = 0; r < 4; ++r) {
      float s = rdlane(xn[r], c);
      a[r][0] = fmaf(s, w0, a[r][0]);
      a[r][1] = fmaf(s, w1, a[r][1]);
      a[r][2] = fmaf(s, w2, a[r][2]);
    }
  }
#pragma unroll
  for (int r = 0; r < 4; ++r) {
    size_t o = (size_t)(row0 + r) * 192 + n0;
    qkv[o] = a[r][0]; qkv[o + 1] = a[r][1]; qkv[o + 2] = a[r][2];
  }
}

// ---------------- K2: KNN via grid — wave-cooperative cube enumeration ----------------
#define KQB 4
__global__ __launch_bounds__(256) void k_knn(
    const float* __restrict__ ccan, const int* __restrict__ mcan,
    const float* __restrict__ csrX, const float* __restrict__ csrY,
    const float* __restrict__ csrZ, const int* __restrict__ csrI,
    const int* __restrict__ cellStart, int* __restrict__ nbr)
{
  __shared__ int cs[513];
  __shared__ int posb[KQB][200];
  __shared__ unsigned long long sbuf[KQB][64];
  const int tid = threadIdx.x;
  const int row0 = blockIdx.x * KQB;
  const int b = row0 >> 12;
  for (int i = tid; i < 513; i += 256) cs[i] = cellStart[b * 513 + i];
  __syncthreads();
  const int wave = tid >> 6, lane = tid & 63;
  const int qi = (row0 & (NV - 1)) + wave;
  const float* cb = ccan + (size_t)b * NV * 3;
  const size_t gb = (size_t)b * NV;
  const float qx = cb[qi * 3], qy = cb[qi * 3 + 1], qz = cb[qi * 3 + 2];
  const int qcx = min(7, max(0, (int)floorf(qx * 0.5f)));
  const int qcy = min(7, max(0, (int)floorf(qy * 0.5f)));
  const int qcz = min(7, max(0, (int)floorf(qz * 0.5f)));
  const int V = cs[512];
  const int grow = row0 + wave;
  const unsigned long long below = (lane == 0) ? 0ull : (~0ull >> (64 - lane));

  bool done = false;
  if (V >= KNN) {
#pragma unroll 1
    for (int s = 1; s <= 6 && !done; ++s) {
      const int x0 = max(0, qcx - s), x1 = min(7, qcx + s);
      const int y0 = max(0, qcy - s), y1 = min(7, qcy + s);
      const int z0 = max(0, qcz - s), z1 = min(7, qcz + s);
      const int ny = y1 - y0 + 1;
      const int nrows = ny * (z1 - z0 + 1);
      // ---- build compact CSR-position list via lane-per-row + shuffle scan ----
      int cnt = 0;
#pragma unroll 1
      for (int base = 0; base < nrows; base += 64) {
        int rr = base + lane;
        int rcnt = 0, p0 = 0;
        if (rr < nrows) {
          int zz = z0 + rr / ny, yy = y0 + rr % ny;
          int cbase = (zz * 8 + yy) * 8;
          p0 = cs[cbase + x0];
          rcnt = cs[cbase + x1 + 1] - p0;
        }
        int incl = rcnt;
#pragma unroll
        for (int off = 1; off < 64; off <<= 1) {
          int o = __shfl_up(incl, off);
          if (lane >= off) incl += o;
        }
        int excl = cnt + incl - rcnt;
        for (int k = 0; k < rcnt; ++k) {
          int pos = excl + k;
          if (pos < 200) posb[wave][pos] = p0 + k;
        }
        cnt += __shfl(incl, 63);
      }
      if (cnt < KNN) continue;
      if (cnt > 192) break;   // -> brute force
      // ---- evaluate candidates (coalesced segment gathers, L2-hot) ----
      unsigned d2b[3]; int pp[3];
#pragma unroll
      for (int u = 0; u < 3; ++u) { d2b[u] = 0xffffffffu; pp[u] = 0; }
#pragma unroll 1
      for (int u = 0; u < 3; ++u) {
        int i = lane + u * 64;
        if (i < cnt) {
          int p = posb[wave][i];
          float d2 = d2f(csrX[gb + p], csrY[gb + p], csrZ[gb + p], qx, qy, qz);
          d2b[u] = __float_as_uint(d2);
          pp[u] = p;
        }
      }
      // ---- T = exact 10th-smallest d2 (ballot binary search, same regs) ----
      unsigned acc = 0;
#pragma unroll 1
      for (int bit = 31; bit >= 0; --bit) {
        unsigned tr = acc | (1u << bit);
        int c4 = __popcll(__ballot(d2b[0] < tr)) + __popcll(__ballot(d2b[1] < tr))
               + __popcll(__ballot(d2b[2] < tr));
        if (c4 <= KNN - 1) acc = tr;
      }
      const unsigned Tb = acc;    // exact 10th-smallest value bits
      // ---- geometric verification: outside points have d2 >= f^2 ----
      {
        float f = 1e30f;
        if (x0 > 0) f = fminf(f, qx - 2.f * x0);
        if (x1 < 7) f = fminf(f, 2.f * (x1 + 1) - qx);
        if (y0 > 0) f = fminf(f, qy - 2.f * y0);
        if (y1 < 7) f = fminf(f, 2.f * (y1 + 1) - qy);
        if (z0 > 0) f = fminf(f, qz - 2.f * z0);
        if (z1 < 7) f = fminf(f, 2.f * (z1 + 1) - qz);
        if (!(__uint_as_float(Tb) < f * f * 0.999f)) continue;   // expand
      }
      // ---- ballot-compact survivors (d2 <= T), then exact rank ----
      int basec = 0;
#pragma unroll 1
      for (int u = 0; u < 3; ++u) {
        bool sv = (d2b[u] <= Tb);
        unsigned long long bal = __ballot(sv);
        if (bal) {
          int pos = basec + __popcll(bal & below);
          if (sv && pos < 64)
            sbuf[wave][pos] = ((unsigned long long)d2b[u] << 32)
                            | (unsigned)csrI[gb + pp[u]];
          basec += __popcll(bal);
        }
      }
      if (basec > 64) break;     // -> brute force
      if (lane < basec) {
        unsigned long long mykey = sbuf[wave][lane];
        int rank = 0;
        for (int i = 0; i < basec; ++i) rank += (sbuf[wave][i] < mykey);
        if (rank < KNN)
          nbr[(size_t)grow * KNN + rank] = (int)(mykey & (NV - 1));
      }
      done = true;
    }
  }

  if (!done) {
    // exact brute force over all NV (jax semantics: invalid -> d2=1e9)
    const int* mb = mcan + b * NV;
    unsigned long long arr[KNN];
#pragma unroll
    for (int t = 0; t < KNN; ++t) arr[t] = ~0ull;
    for (int j = lane; j < NV; j += 64) {
      float d2 = d2f(cb[j * 3], cb[j * 3 + 1], cb[j * 3 + 2], qx, qy, qz);
      if (!mb[j]) d2 = 1e9f;
      unsigned long long key =
          ((unsigned long long)__float_as_uint(d2) << 32) | (unsigned)j;
      if (key < arr[KNN - 1]) {
        arr[KNN - 1] = key;
#pragma unroll
        for (int t2 = KNN - 1; t2 > 0; --t2) {
          unsigned long long a = arr[t2 - 1], cc2 = arr[t2];
          if (cc2 < a) { arr[t2 - 1] = cc2; arr[t2] = a; }
        }
      }
    }
    unsigned myj = 0;
#pragma unroll 1
    for (int r = 0; r < KNN; ++r) {
      unsigned hi = (unsigned)(arr[0] >> 32);
      unsigned lo = (unsigned)(arr[0] & 0xffffffffu);
      unsigned ohi = hi, olo = lo;
      wave_min_kv(hi, lo);
      if (ohi == hi && olo == lo) {   // unique keys: owner pops
#pragma unroll
        for (int t = 0; t < KNN - 1; ++t) arr[t] = arr[t + 1];
        arr[KNN - 1] = ~0ull;
      }
      if (lane == r) myj = lo;
    }
    if (lane < KNN)
      nbr[(size_t)grow * KNN + lane] = (int)(myj & (NV - 1));
  }
}

// ---------------- K3: attention + proj + residual (R9 version) ----------------
#define AROWS 4
__global__ __launch_bounds__(256) void k_attn(
    const float* __restrict__ qkv, const int* __restrict__ nbr,
    const int* __restrict__ mcan, const float* __restrict__ xcan,
    const float* __restrict__ pcan, float* __restrict__ xres)
{
  __shared__ float wp[CH * CH];   // 16 KB wproj [c][n]
  __shared__ float bp[CH];
  __shared__ float sc[AROWS][NH][KNN];
  __shared__ float wsel[AROWS][NH][KS];
  __shared__ int   isel[AROWS][NH][KS];
  __shared__ float obuf[AROWS][CH];
  __shared__ int   nb[AROWS][KNN];
  __shared__ float npen[AROWS][KNN];
  const int tid = threadIdx.x;
  {
    const float4* src = (const float4*)(pcan + P_WPROJ);
    float4* dst = (float4*)wp;
    for (int i = tid; i < CH * CH / 4; i += 256) dst[i] = src[i];
    if (tid < CH) bp[tid] = pcan[P_BPROJ + tid];
  }
  const int wave = tid >> 6, lane = tid & 63;
  const int row = blockIdx.x * AROWS + wave;
  const int b = row / NV;

  if (lane < KNN) {
    int j = nbr[(size_t)row * KNN + lane] & (NV - 1);
    nb[wave][lane] = j;
    npen[wave][lane] = mcan[b * NV + j] ? 0.0f : -1e9f;
  }
  __syncthreads();

  if (lane < NH * KNN) {
    int h = lane / KNN, kk = lane % KNN;
    int j = nb[wave][kk];
    const float* qp = qkv + (size_t)row * 192 + h * DH;
    const float* kp = qkv + ((size_t)(b * NV + j)) * 192 + 64 + h * DH;
    float acc = 0.f;
#pragma unroll
    for (int d = 0; d < DH; ++d) acc += qp[d] * kp[d];
    sc[wave][h][kk] = acc * 0.25f + npen[wave][kk];
  }
  __syncthreads();

  if (lane < NH) {
    int h = lane;
    float sv[KS]; int sj[KS];
    unsigned used = 0;
#pragma unroll
    for (int r = 0; r < KS; ++r) {
      float best = -INFINITY; int bi = 0;
#pragma unroll
      for (int kk = 0; kk < KNN; ++kk) {
        float s = sc[wave][h][kk];
        if (!(used & (1u << kk)) && s > best) { best = s; bi = kk; }
      }
      used |= 1u << bi; sv[r] = best; sj[r] = bi;
    }
    float mx = sv[0];
    float e[KS], sum = 0.f;
#pragma unroll
    for (int r = 0; r < KS; ++r) { e[r] = expf(sv[r] - mx); sum += e[r]; }
    float inv = 1.0f / sum;
#pragma unroll
    for (int r = 0; r < KS; ++r) {
      wsel[wave][h][r] = e[r] * inv;
      isel[wave][h][r] = nb[wave][sj[r]];
    }
  }
  __syncthreads();

  {
    int h = lane >> 4, d = lane & 15;
    float o = 0.f;
#pragma unroll
    for (int r = 0; r < KS; ++r) {
      int j = isel[wave][h][r];
      o += wsel[wave][h][r] * qkv[((size_t)(b * NV + j)) * 192 + 128 + h * DH + d];
    }
    obuf[wave][lane] = o;
  }
  __syncthreads();

  {
    float acc = bp[lane];
#pragma unroll 4
    for (int cc = 0; cc < CH; ++cc)
      acc = fmaf(obuf[wave][cc], wp[cc * CH + lane], acc);
    float a = mcan[row] ? acc : 0.0f;
    xres[(size_t)row * CH + lane] = 0.5f * a + xcan[(size_t)row * CH + lane];
  }
}

// ---------------- K4: LN2 + MLP + residual (R9 version) ----------------
__global__ __launch_bounds__(256) void k_mlp(
    const float* __restrict__ xres, const float* __restrict__ pcan,
    const int* __restrict__ flags, void* __restrict__ out)
{
  __shared__ unsigned short w1b[CH * MHID];   // [c][n] 32 KB bf16
  const int tid = threadIdx.x;
  for (int i = tid; i < CH * MHID; i += 256)
    w1b[i] = __bfloat16_as_ushort(__float2bfloat16(pcan[P_W1 + i]));
  __syncthreads();
  const int wave = tid >> 6, lane = tid & 63;
  const int row0 = blockIdx.x * 16 + wave * 4;
  const float gg = pcan[P_LN2G + lane], bb = pcan[P_LN2B + lane];

  float xn[4], xv[4];
#pragma unroll
  for (int r = 0; r < 4; ++r) {
    float v = xres[(size_t)(row0 + r) * CH + lane];
    xv[r] = v;
    float m = wave_sum_f32(v) * (1.0f / 64.0f);
    float d = v - m;
    float var = wave_sum_f32(d * d) * (1.0f / 64.0f);
    float rs = 1.0f / sqrtf(var + 1e-5f);
    xn[r] = d * rs * gg + bb;
  }

  const int n0 = 4 * lane;
  float g[4][4];
  {
    float4 bi = *(const float4*)(pcan + P_B1 + n0);
#pragma unroll
    for (int r = 0; r < 4; ++r) {
      g[r][0] = bi.x; g[r][1] = bi.y; g[r][2] = bi.z; g[r][3] = bi.w;
    }
  }
  for (int c = 0; c < CH; ++c) {
    ushort4 w4 = *(const ushort4*)&w1b[c * MHID + n0];
    float w0 = b2f(__ushort_as_bfloat16(w4.x));
    float w1 = b2f(__ushort_as_bfloat16(w4.y));
    float w2 = b2f(__ushort_as_bfloat16(w4.z));
    float w3 = b2f(__ushort_as_bfloat16(w4.w));
#pragma unroll
    for (int r = 0; r < 4; ++r) {
      float s = rdlane(xn[r], c);
      g[r][0] = fmaf(s, w0, g[r][0]);
      g[r][1] = fmaf(s, w1, g[r][1]);
      g[r][2] = fmaf(s, w2, g[r][2]);
      g[r][3] = fmaf(s, w3, g[r][3]);
    }
  }
#pragma unroll
  for (int r = 0; r < 4; ++r)
#pragma unroll
    for (int i = 0; i < 4; ++i) {
      float t = g[r][i];
      float u = 0.7978845608028654f * (t + 0.044715f * t * t * t);
      g[r][i] = 0.5f * t * (1.0f + tanh_fast(u));
    }

  float acc2[4];
  {
    float bo = pcan[P_B2 + lane];
#pragma unroll
    for (int r = 0; r < 4; ++r) acc2[r] = bo;
  }
  const float* w2p = pcan + P_W2 + lane;
#pragma unroll 2
  for (int hb = 0; hb < MHID / 4; ++hb) {
#pragma unroll
    for (int i = 0; i < 4; ++i) {
      float wv = w2p[(hb * 4 + i) * CH];
#pragma unroll
      for (int r = 0; r < 4; ++r)
        acc2[r] = fmaf(rdlane(g[r][i], hb), wv, acc2[r]);
    }
  }
#pragma unroll
  for (int r = 0; r < 4; ++r) {
    float o = 0.5f * acc2[r] + xv[r];
    size_t idx = (size_t)(row0 + r) * CH + lane;
    if (flags[0]) ((bf16*)out)[idx] = __float2bfloat16(o);
    else          ((float*)out)[idx] = o;
  }
}

extern "C" void kernel_launch(void* const* d_in, const int* in_sizes, int n_in,
                              void* d_out, int out_size, void* d_ws, size_t ws_size,
                              hipStream_t stream)
{
  char* ws = (char*)d_ws;
  float* qkv   = (float*)(ws);
  float* xres  = (float*)(ws + 12582912);
  float* xcan  = (float*)(ws + 16777216);
  float* ccan  = (float*)(ws + 20971520);
  float* pcan  = (float*)(ws + 21168128);
  int*   mcan  = (int*)  (ws + 21368064);
  int*   nbr   = (int*)  (ws + 21433600);
  int*   flags = (int*)  (ws + 22088960);
  float* csrX  = (float*)(ws + 22089728);
  float* csrY  = (float*)(ws + 22155264);
  float* csrZ  = (float*)(ws + 22220800);
  int*   csrI  = (int*)  (ws + 22286336);
  int*   cellS = (int*)  (ws + 22351872);

  k_detect<<<1, 64, 0, stream>>>((const unsigned short*)d_in[0],
                                 (const unsigned*)d_in[2], flags);
  const int total = BN * CH + NB * NV * 3 + P_TOT + BN;
  k_ingest<<<(total + 255) / 256, 256, 0, stream>>>(
      d_in[0], d_in[1], d_in[2], d_in[3], d_in[4], d_in[5], d_in[6],
      d_in[7], d_in[8], d_in[9], d_in[10], d_in[11], d_in[12], d_in[13], d_in[14],
      flags, xcan, ccan, pcan, mcan);
  k_grid<<<NB, 256, 0, stream>>>(ccan, mcan, csrX, csrY, csrZ, csrI, cellS);
  k_ln_qkv<<<BN / 16, 256, 0, stream>>>(xcan, pcan, qkv);
  k_knn<<<BN / KQB, 256, 0, stream>>>(ccan, mcan, csrX, csrY, csrZ, csrI,
                                      cellS, nbr);
  k_attn<<<BN / AROWS, 256, 0, stream>>>(qkv, nbr, mcan, xcan, pcan, xres);
  k_mlp<<<BN / 16, 256, 0, stream>>>(xres, pcan, flags, d_out);
}